// Round 12
// baseline (134.228 us; speedup 1.0000x reference)
//
#include <hip/hip_runtime.h>
#include <stdint.h>

#define T_ROWS 1500000
#define N_ROWS 2000000
#define N_SEL  1048576
#define G_CNT  (N_SEL/4)
#define LB     (N_ROWS - N_SEL)
#define TILE   4096
#define NBLK   ((N_ROWS + TILE - 1)/TILE)     // 489
#define NBLK1  (NBLK + 1)                      // 490 (row stride; last col = total)
#define STHREADS 1024                          // scatter block (16 waves)
#define SWAVES 16
#define WTILE  (TILE/SWAVES)                   // 256
#define WROUNDS (WTILE/64)                     // 4
#define HTHREADS 512
#define BINS   256
#define NB_MX  ((T_ROWS + HTHREADS - 1)/HTHREADS)

static_assert((uint64_t)NBLK * TILE >= N_ROWS, "tile coverage");
static_assert(T_ROWS < (1 << 21), "tp fits 21 bits");
static_assert((LB * 4) % 16 == 0, "finalize uint4 alignment");

// Split representation: K[i] = descending-orderable key (asc uint == desc float),
// P[i] = (flag!=0 << 21) | tp. Both permuted identically each pass; LSD radix over
// K's 4 bytes is stable -> ties keep original (index-ascending) order ==
// jnp.argsort(-bt). P carries everything finalize needs.
// build fuses K/P emit + mxtab + pass-0 per-tile histogram (uniform low byte).
__global__ __launch_bounds__(HTHREADS) void build_all(
        const float* __restrict__ nb, const float* __restrict__ td,
        uint32_t* __restrict__ K, uint32_t* __restrict__ P,
        float* __restrict__ mxtab, uint32_t* __restrict__ gH) {
    const int b = blockIdx.x;
    if (b >= NBLK) {
        int i = (b - NBLK) * HTHREADS + threadIdx.x;
        if (i < T_ROWS) {
            float4 r = *(const float4*)(td + (size_t)i * 4);
            mxtab[i] = fmaxf(r.y, fmaxf(r.z, r.w));
        }
        return;
    }
    __shared__ uint32_t h[BINS];
    const int t = threadIdx.x;
    if (t < BINS) h[t] = 0;
    __syncthreads();
    const int base = b * TILE;
    #pragma unroll
    for (int r = 0; r < TILE / HTHREADS; ++r) {
        int i = base + r * HTHREADS + t;
        if (i < N_ROWS) {
            const float* row = nb + (size_t)i * 5;
            uint32_t u = __float_as_uint(row[1]);
            uint32_t ku = (u & 0x80000000u) ? ~u : (u | 0x80000000u);
            uint32_t kd = ~ku;
            uint32_t tp = (uint32_t)(int)row[0];     // exact: integral f32
            uint32_t fl = (row[4] != 0.0f) ? 1u : 0u;
            K[i] = kd;
            P[i] = (fl << 21) | tp;
            atomicAdd(&h[kd & (BINS - 1)], 1u);      // uniform byte: plain atomics
        }
    }
    __syncthreads();
    if (t < BINS) gH[(size_t)t * NBLK1 + b] = h[t];
}

// Uniform-digit histogram (mantissa bytes): uint4 = 4 keys/load, plain LDS atomics.
template <int SHIFT>
__global__ __launch_bounds__(HTHREADS) void radix_hist_u(
        const uint32_t* __restrict__ K, uint32_t* __restrict__ gH) {
    __shared__ uint32_t h[BINS];
    const int t = threadIdx.x;
    if (t < BINS) h[t] = 0;
    __syncthreads();
    const uint4* s4 = (const uint4*)(K + (size_t)blockIdx.x * TILE);
    const int quadBase = blockIdx.x * (TILE / 4);
    #pragma unroll
    for (int r = 0; r < TILE / (4 * HTHREADS); ++r) {
        int j = r * HTHREADS + t;                 // quad index within tile
        uint4 v = s4[j];                          // keys 4j..4j+3 (ws mapped past end)
        int i0 = (quadBase + j) * 4;
        if (i0 < N_ROWS)     atomicAdd(&h[(v.x >> SHIFT) & (BINS - 1)], 1u);
        if (i0 + 1 < N_ROWS) atomicAdd(&h[(v.y >> SHIFT) & (BINS - 1)], 1u);
        if (i0 + 2 < N_ROWS) atomicAdd(&h[(v.z >> SHIFT) & (BINS - 1)], 1u);
        if (i0 + 3 < N_ROWS) atomicAdd(&h[(v.w >> SHIFT) & (BINS - 1)], 1u);
    }
    __syncthreads();
    if (t < BINS) gH[(size_t)t * NBLK1 + blockIdx.x] = h[t];
}

// Skewed-digit histogram (top byte: sign+exponent): ballot-leader counting.
template <int SHIFT>
__global__ __launch_bounds__(HTHREADS) void radix_hist_s(
        const uint32_t* __restrict__ K, uint32_t* __restrict__ gH) {
    __shared__ uint32_t h[BINS];
    const int t = threadIdx.x;
    const int lane = t & 63;
    if (t < BINS) h[t] = 0;
    __syncthreads();
    const int base = blockIdx.x * TILE;
    #pragma unroll
    for (int r = 0; r < TILE / HTHREADS; ++r) {
        int i = base + r * HTHREADS + t;
        bool active = (i < N_ROWS);
        uint32_t d = 0;
        if (active) d = (K[i] >> SHIFT) & (BINS - 1);
        uint64_t m = __ballot(active ? 1 : 0);
        #pragma unroll
        for (int bb = 0; bb < 8; ++bb) {
            uint64_t x = __ballot((active && ((d >> bb) & 1u)) ? 1 : 0);
            m = ((d >> bb) & 1u) ? (m & x) : (m & ~x);
        }
        int ldr = __ffsll((unsigned long long)m) - 1;
        if (active && lane == ldr) atomicAdd(&h[d], (uint32_t)__popcll(m));
    }
    __syncthreads();
    if (t < BINS) gH[(size_t)t * NBLK1 + blockIdx.x] = h[t];
}

// one block per digit: exclusive scan of contiguous row; total -> row[NBLK]
__global__ void radix_rowscan(uint32_t* __restrict__ gH) {
    const int d = blockIdx.x;
    const int lane = threadIdx.x;
    uint32_t* row = gH + (size_t)d * NBLK1;
    uint32_t carry = 0;
    for (int b0 = 0; b0 < NBLK; b0 += 64) {
        int i = b0 + lane;
        uint32_t v = (i < NBLK) ? row[i] : 0u;
        uint32_t s = v;
        #pragma unroll
        for (int off = 1; off < 64; off <<= 1) {
            uint32_t tt = __shfl_up(s, off, 64);
            if (lane >= off) s += tt;
        }
        if (i < NBLK) row[i] = s - v + carry;
        carry += __shfl(s, 63, 64);
    }
    if (lane == 0) row[NBLK] = carry;
}

// 16-wave scatter, split K/P streams. cnt32 [wave][digit] (bank-conflict-free).
template <int SHIFT, bool LAST>
__global__ __launch_bounds__(STHREADS) void radix_scatter(
        const uint32_t* __restrict__ K, const uint32_t* __restrict__ P,
        uint32_t* __restrict__ Kd, uint32_t* __restrict__ Pd,
        const uint32_t* __restrict__ gH) {
    __shared__ uint32_t keyS[TILE];               // 16 KB
    __shared__ uint32_t payS[TILE];               // 16 KB
    __shared__ uint32_t cnt32[SWAVES * BINS];     // 16 KB [wave][digit]
    __shared__ uint32_t writeBase[BINS];
    __shared__ uint32_t wpT[SWAVES], wpL[SWAVES];

    const int t = threadIdx.x;
    const int lane = t & 63;
    const int w = t >> 6;
    const int blk = blockIdx.x;
    const int base = blk * TILE;
    const int tileCount = (N_ROWS - base < TILE) ? (N_ROWS - base) : TILE;

    // early issue: this block's prefix data (scanned rows, plain cached loads)
    uint32_t rp = 0, lc = 0, tot = 0;
    if (t < BINS) {
        const uint32_t* row = gH + (size_t)t * NBLK1;
        rp = row[blk];
        lc = row[blk + 1] - rp;
        tot = row[NBLK];
    }

    #pragma unroll
    for (int k = t; k < SWAVES * BINS; k += STHREADS) cnt32[k] = 0u;
    __syncthreads();

    // ---- phase A: per-wave digit counts via ballot match; keys only (8 MB stream)
    uint32_t creg[WROUNDS];
    uint32_t meta[WROUNDS];
    const uint64_t below = (lane == 0) ? 0ull : (~0ull >> (64 - lane));
    #pragma unroll
    for (int r = 0; r < WROUNDS; ++r) {
        int idx = base + w * WTILE + r * 64 + lane;
        bool active = (idx < N_ROWS);
        uint32_t c = active ? K[idx] : 0u;
        creg[r] = c;
        uint32_t d = (c >> SHIFT) & (BINS - 1);
        uint64_t m = __ballot(active ? 1 : 0);
        #pragma unroll
        for (int bb = 0; bb < 8; ++bb) {
            uint64_t x = __ballot((active && ((d >> bb) & 1u)) ? 1 : 0);
            m = ((d >> bb) & 1u) ? (m & x) : (m & ~x);
        }
        int ldr = __ffsll((unsigned long long)m) - 1;
        uint32_t cnt = (uint32_t)__popcll(m);
        uint32_t rank = (uint32_t)__popcll(m & below);
        meta[r] = rank | ((uint32_t)(ldr < 0 ? 0 : ldr) << 8) | (cnt << 16);
        if (active && lane == ldr)
            atomicAdd(&cnt32[w * BINS + d], cnt);
    }
    __syncthreads();   // cnt32 complete

    // ---- phase B1: dual block-exclusive scans over digits (tot -> exT, lc -> exL)
    uint32_t sT = tot, sL = lc;
    #pragma unroll
    for (int off = 1; off < 64; off <<= 1) {
        uint32_t aT = __shfl_up(sT, off, 64);
        uint32_t aL = __shfl_up(sL, off, 64);
        if (lane >= off) { sT += aT; sL += aL; }
    }
    if (lane == 63) { wpT[w] = sT; wpL[w] = sL; }
    __syncthreads();
    uint32_t exT = sT - tot, exL = sL - lc;
    #pragma unroll
    for (int wv = 0; wv < SWAVES; ++wv) if (wv < w) { exT += wpT[wv]; exL += wpL[wv]; }

    // ---- phase B2: writeBase + per-wave cursors (thread t owns digit t)
    if (t < BINS) {
        writeBase[t] = exT + rp - exL;
        uint32_t run = exL;
        #pragma unroll
        for (int wv = 0; wv < SWAVES; ++wv) {
            uint32_t c0 = cnt32[wv * BINS + t];
            cnt32[wv * BINS + t] = run;
            run += c0;
        }
    }
    __syncthreads();

    // ---- phase C: ballot-free — leader atomicAdd on cursor, shfl, LDS scatter (K+P)
    #pragma unroll
    for (int r = 0; r < WROUNDS; ++r) {
        int idx = base + w * WTILE + r * 64 + lane;
        bool active = (idx < N_ROWS);
        uint32_t pv = active ? P[idx] : 0u;       // payload stream overlaps LDS work
        uint32_t c = creg[r];
        uint32_t d = (c >> SHIFT) & (BINS - 1);
        uint32_t mt = meta[r];
        uint32_t rank = mt & 0xFFu;
        int ldr = (int)((mt >> 8) & 0xFFu);
        uint32_t cnt = mt >> 16;
        uint32_t before = 0;
        if (active && lane == ldr)
            before = atomicAdd(&cnt32[w * BINS + d], cnt);
        before = __shfl(before, ldr, 64);
        if (active) {
            uint32_t q = before + rank;
            keyS[q] = c;
            payS[q] = pv;
        }
    }
    __syncthreads();

    // ---- write-out: consecutive sorted positions share digit -> coalesced segments
    #pragma unroll
    for (int r = 0; r < TILE / STHREADS; ++r) {
        int p = r * STHREADS + t;
        if (p < tileCount) {
            uint32_t c = keyS[p];
            uint32_t d = (c >> SHIFT) & (BINS - 1);
            uint32_t g = writeBase[d] + p;
            if (!LAST) {
                Kd[(size_t)g] = c;
                Pd[(size_t)g] = payS[p];
            } else if (g >= LB) {        // only selected range is read; payload only
                Pd[(size_t)g] = payS[p];
            }
        }
    }
}

__global__ void finalize(const uint32_t* __restrict__ pay, const float* __restrict__ td,
                         const float* __restrict__ mxtab, float* __restrict__ out) {
    int g = blockIdx.x * 256 + threadIdx.x;
    if (g >= G_CNT) return;
    uint4 p4 = *(const uint4*)(pay + LB + (size_t)g * 4);
    uint32_t cs[4] = {p4.x, p4.y, p4.z, p4.w};
    float maxmin = -100000.0f;
    int maxindex = -100;
    #pragma unroll
    for (int j = 0; j < 4; ++j) {
        int tp = (int)(cs[j] & 0x1FFFFFu);
        bool re1 = ((cs[j] >> 21) & 1u) != 0u;
        float mx = mxtab[tp];
        bool gt = (mx > maxmin);
        if (re1 == gt) { maxmin = mx; maxindex = tp; }
    }
    int mi = maxindex < 0 ? 0 : maxindex;   // clip lower bound; upper never binds
    float4 row = *(const float4*)(td + (size_t)mi * 4);
    *(float4*)(out + (size_t)g * 4) = row;
}

extern "C" void kernel_launch(void* const* d_in, const int* in_sizes, int n_in,
                              void* d_out, int out_size, void* d_ws, size_t ws_size,
                              hipStream_t stream) {
    const float* td = (const float*)d_in[0];
    const float* nb = (const float*)d_in[1];
    float* out = (float*)d_out;
    uint8_t* ws = (uint8_t*)d_ws;

    // layout: mxtab 6MB | gH ~490KB | K_A,P_A,K_B,P_B 8MB each (ends ~37.5MB)
    const size_t SZ = 8000000;   // 2M * 4B
    float*    mxtab = (float*)(ws);
    uint32_t* gH    = (uint32_t*)(ws + (size_t)6 * 1024 * 1024);
    uint32_t* K_A   = (uint32_t*)(ws + (size_t)7 * 1024 * 1024);
    uint32_t* P_A   = (uint32_t*)(ws + (size_t)7 * 1024 * 1024 + SZ);
    uint32_t* K_B   = (uint32_t*)(ws + (size_t)7 * 1024 * 1024 + 2 * SZ);
    uint32_t* P_B   = (uint32_t*)(ws + (size_t)7 * 1024 * 1024 + 3 * SZ);

    build_all<<<NBLK + NB_MX, HTHREADS, 0, stream>>>(nb, td, K_A, P_A, mxtab, gH);

    // pass 0: key bits [0,8) — histogram fused into build
    radix_rowscan<<<BINS, 64, 0, stream>>>(gH);
    radix_scatter<0, false><<<NBLK, STHREADS, 0, stream>>>(K_A, P_A, K_B, P_B, gH);

    // pass 1: bits [8,16) — uniform digit
    radix_hist_u<8><<<NBLK, HTHREADS, 0, stream>>>(K_B, gH);
    radix_rowscan<<<BINS, 64, 0, stream>>>(gH);
    radix_scatter<8, false><<<NBLK, STHREADS, 0, stream>>>(K_B, P_B, K_A, P_A, gH);

    // pass 2: bits [16,24) — uniform digit
    radix_hist_u<16><<<NBLK, HTHREADS, 0, stream>>>(K_A, gH);
    radix_rowscan<<<BINS, 64, 0, stream>>>(gH);
    radix_scatter<16, false><<<NBLK, STHREADS, 0, stream>>>(K_A, P_A, K_B, P_B, gH);

    // pass 3: bits [24,32) — skewed digit; payload-only writes in selected range
    radix_hist_s<24><<<NBLK, HTHREADS, 0, stream>>>(K_B, gH);
    radix_rowscan<<<BINS, 64, 0, stream>>>(gH);
    radix_scatter<24, true><<<NBLK, STHREADS, 0, stream>>>(K_B, P_B, nullptr, P_A, gH);

    finalize<<<(G_CNT + 255) / 256, 256, 0, stream>>>(P_A, td, mxtab, out);
}